// Round 9
// baseline (352.718 us; speedup 1.0000x reference)
//
#include <hip/hip_runtime.h>
#include <hip/hip_bf16.h>

#define BATCH 16
#define SEQ   2048
#define HD    128
#define QBLK  64
#define KVBLK 32
#define KVHALF 1024
#define NTG   (KVHALF / KVBLK)   // 32 KV tiles per group

typedef __attribute__((ext_vector_type(8))) short bf16x8;
typedef __attribute__((ext_vector_type(4))) float f32x4;
typedef __attribute__((ext_vector_type(4))) short s16x4;

__device__ __forceinline__ short f2bf(float x) {
    __hip_bfloat16 h = __float2bfloat16(x);
    return *reinterpret_cast<short*>(&h);
}

// 8 waves = 2 KV-groups x 4 waves. Group g covers kv in [g*1024,(g+1)*1024).
// LDS 52KB -> 2 blocks/CU -> 16 waves/CU (double round-8's occupancy).
__global__ __launch_bounds__(512, 4)
void attn_fused(const float* __restrict__ Q, const float* __restrict__ K,
                const float* __restrict__ V, const float* __restrict__ ISF,
                float* __restrict__ O)
{
    const int tid  = threadIdx.x;
    const int lane = tid & 63;
    const int wv   = tid >> 6;       // 0..7
    const int w4   = wv & 3;         // wave within group: q-rows [w4*16, w4*16+16)
    const int g    = wv >> 2;        // KV group 0/1
    const int gtid = (w4 << 6) | lane;   // 0..255 within group
    const int lg   = lane >> 4;
    const int lc   = lane & 15;

    const int b    = blockIdx.x >> 5;
    const int q0   = (blockIdx.x & 31) * QBLK;

    // carved shared block: Klds [2 grp][2 buf][4096 shorts] = 32KB,
    // Vtlds [2 grp][5120 shorts] = 20KB; merge buffer (40KB) reuses the front.
    __shared__ __align__(16) char sMem[53248];
    short* Klds  = (short*)sMem;
    short* Vtlds = (short*)(sMem + 32768);

    // ---- Q fragments (A operand): row = q0 + w4*16 + lc, k = ks*32 + lg*8 + j ----
    bf16x8 qf[4];
    {
        const float* qrow = Q + ((size_t)b * SEQ + q0 + w4 * 16 + lc) * HD;
        #pragma unroll
        for (int ks = 0; ks < 4; ++ks) {
            const float* p = qrow + ks * 32 + lg * 8;
            float4 x0 = *reinterpret_cast<const float4*>(p);
            float4 x1 = *reinterpret_cast<const float4*>(p + 4);
            bf16x8 f;
            f[0]=f2bf(x0.x); f[1]=f2bf(x0.y); f[2]=f2bf(x0.z); f[3]=f2bf(x0.w);
            f[4]=f2bf(x1.x); f[5]=f2bf(x1.y); f[6]=f2bf(x1.z); f[7]=f2bf(x1.w);
            qf[ks] = f;
        }
    }

    f32x4 oacc[8];
    #pragma unroll
    for (int i = 0; i < 8; ++i) oacc[i] = (f32x4){0.f, 0.f, 0.f, 0.f};
    float m_r[4] = {-INFINITY, -INFINITY, -INFINITY, -INFINITY};
    float l_r[4] = {0.f, 0.f, 0.f, 0.f};

    const float* kbase = K + (size_t)b * SEQ * HD;
    const float* vbase = V + (size_t)b * SEQ * HD;
    const float* ibase = ISF + ((size_t)b * SEQ + q0 + w4 * 16) * SEQ;
    const int kvbase = g * KVHALF;
    const int kofs   = g * 8192;     // group base into Klds (shorts)
    const int vofs   = g * 5120;     // group base into Vtlds (shorts)

    float4 kreg[4];
    float  vreg[4][4];
    float  isf_cur[8], isf_nxt[8];

    auto LOAD = [&](int kv0) {
        const float* kb = kbase + (size_t)kv0 * HD;
        const float* vb = vbase + (size_t)kv0 * HD;
        #pragma unroll
        for (int r = 0; r < 4; ++r) {
            int idx = r * 256 + gtid;
            kreg[r] = *reinterpret_cast<const float4*>(kb + (size_t)(idx >> 5) * HD + (idx & 31) * 4);
        }
        #pragma unroll
        for (int r = 0; r < 4; ++r) {
            int idx = r * 256 + gtid;
            int d = idx & 127, kq = idx >> 7;
            #pragma unroll
            for (int j = 0; j < 4; ++j)
                vreg[r][j] = vb[(size_t)(kq * 4 + j) * HD + d];
        }
    };
    auto LOAD_ISF = [&](int kv0, float* dst) {
        #pragma unroll
        for (int nt = 0; nt < 2; ++nt)
            #pragma unroll
            for (int r = 0; r < 4; ++r)
                dst[nt * 4 + r] = ibase[(size_t)(lg * 4 + r) * SEQ + kv0 + nt * 16 + lc];
    };
    auto STOREK = [&](int buf) {
        #pragma unroll
        for (int r = 0; r < 4; ++r) {
            int idx = r * 256 + gtid;
            int kvr = idx >> 5, d4 = idx & 31;
            s16x4 s;
            s[0]=f2bf(kreg[r].x); s[1]=f2bf(kreg[r].y); s[2]=f2bf(kreg[r].z); s[3]=f2bf(kreg[r].w);
            int chunk = (d4 >> 1) ^ (kvr & 7);
            *reinterpret_cast<s16x4*>(&Klds[kofs + buf * 4096 + kvr * 128 + chunk * 8 + (d4 & 1) * 4]) = s;
        }
    };
    auto STOREV = [&]() {
        #pragma unroll
        for (int r = 0; r < 4; ++r) {
            int idx = r * 256 + gtid;
            int d = idx & 127, kq = idx >> 7;
            s16x4 s;
            #pragma unroll
            for (int j = 0; j < 4; ++j) s[j] = f2bf(vreg[r][j]);
            *reinterpret_cast<s16x4*>(&Vtlds[vofs + d * 40 + kq * 4]) = s;
        }
    };

    // ---- prologue: stage tile 0 of this group's half ----
    LOAD(kvbase);
    LOAD_ISF(kvbase, isf_cur);
    STOREK(0);
    STOREV();
    __syncthreads();

    int cur = 0;
    for (int t = 0; t < NTG; ++t) {
        const bool more = (t + 1 < NTG);
        if (more) { LOAD(kvbase + (t + 1) * KVBLK); LOAD_ISF(kvbase + (t + 1) * KVBLK, isf_nxt); }

        // ---- S = Q·K^T ----
        f32x4 sacc[2];
        sacc[0] = (f32x4){0.f,0.f,0.f,0.f};
        sacc[1] = (f32x4){0.f,0.f,0.f,0.f};
        #pragma unroll
        for (int nt = 0; nt < 2; ++nt) {
            int n = lc + nt * 16;
            #pragma unroll
            for (int ks = 0; ks < 4; ++ks) {
                int chunk = (ks * 4 + lg) ^ (n & 7);
                bf16x8 bf = *reinterpret_cast<const bf16x8*>(&Klds[kofs + cur * 4096 + n * 128 + chunk * 8]);
                sacc[nt] = __builtin_amdgcn_mfma_f32_16x16x32_bf16(qf[ks], bf, sacc[nt], 0, 0, 0);
            }
        }

        // ---- scale by 1/isf, online softmax ----
        float sc[2][4], pmax[4];
        #pragma unroll
        for (int r = 0; r < 4; ++r) {
            sc[0][r] = sacc[0][r] * __builtin_amdgcn_rcpf(isf_cur[r]);
            sc[1][r] = sacc[1][r] * __builtin_amdgcn_rcpf(isf_cur[4 + r]);
            pmax[r]  = fmaxf(sc[0][r], sc[1][r]);
        }
        #pragma unroll
        for (int msk = 1; msk < 16; msk <<= 1)
            #pragma unroll
            for (int r = 0; r < 4; ++r)
                pmax[r] = fmaxf(pmax[r], __shfl_xor(pmax[r], msk, 64));

        float alpha[4];
        #pragma unroll
        for (int r = 0; r < 4; ++r) {
            float mn = fmaxf(m_r[r], pmax[r]);
            alpha[r] = __builtin_amdgcn_exp2f((m_r[r] - mn) * 1.44269504f);
            m_r[r]   = mn;
        }

        float rsum[4] = {0.f, 0.f, 0.f, 0.f};
        short pb[2][4];
        #pragma unroll
        for (int nt = 0; nt < 2; ++nt)
            #pragma unroll
            for (int r = 0; r < 4; ++r) {
                float p = __builtin_amdgcn_exp2f((sc[nt][r] - m_r[r]) * 1.44269504f);
                rsum[r] += p;
                pb[nt][r] = f2bf(p);
            }
        #pragma unroll
        for (int msk = 1; msk < 16; msk <<= 1)
            #pragma unroll
            for (int r = 0; r < 4; ++r)
                rsum[r] += __shfl_xor(rsum[r], msk, 64);
        #pragma unroll
        for (int r = 0; r < 4; ++r)
            l_r[r] = l_r[r] * alpha[r] + rsum[r];
        #pragma unroll
        for (int dt = 0; dt < 8; ++dt)
            #pragma unroll
            for (int r = 0; r < 4; ++r)
                oacc[dt][r] *= alpha[r];

        // barrier #1: all waves done reading K[cur]; V(t) of every wave visible
        __syncthreads();

        // ---- P: D-layout -> A-frag via this wave's slice of the retired K buffer ----
        short* pw = &Klds[kofs + cur * 4096 + w4 * 1024];   // 640 < 1024 shorts used
        #pragma unroll
        for (int nt = 0; nt < 2; ++nt)
            #pragma unroll
            for (int r = 0; r < 4; ++r)
                pw[(lg * 4 + r) * 40 + nt * 16 + lc] = pb[nt][r];
        bf16x8 pa = *reinterpret_cast<const bf16x8*>(&pw[lc * 40 + lg * 8]);

        // ---- O += P·V ----
        #pragma unroll
        for (int dt = 0; dt < 8; ++dt) {
            bf16x8 vf = *reinterpret_cast<const bf16x8*>(&Vtlds[vofs + (lc + dt * 16) * 40 + lg * 8]);
            oacc[dt] = __builtin_amdgcn_mfma_f32_16x16x32_bf16(pa, vf, oacc[dt], 0, 0, 0);
        }

        if (more) STOREK(cur ^ 1);
        // barrier #2: K(t+1) visible; all PV(t) reads of Vt done -> safe to overwrite V
        __syncthreads();
        if (more) STOREV();

        cur ^= 1;
        #pragma unroll
        for (int i = 0; i < 8; ++i) isf_cur[i] = isf_nxt[i];
    }

    // ---- merge the two KV-half partials (exact online-softmax merge) ----
    __syncthreads();
    float* mbuf = reinterpret_cast<float*>(sMem);   // 256 lanes * 40 floats = 40KB
    float4* mrow = reinterpret_cast<float4*>(mbuf + (size_t)gtid * 40);
    if (g == 1) {
        #pragma unroll
        for (int dt = 0; dt < 8; ++dt)
            mrow[dt] = (float4){oacc[dt][0], oacc[dt][1], oacc[dt][2], oacc[dt][3]};
        mrow[8] = (float4){m_r[0], m_r[1], m_r[2], m_r[3]};
        mrow[9] = (float4){l_r[0], l_r[1], l_r[2], l_r[3]};
    }
    __syncthreads();
    if (g == 0) {
        float4 m1v = mrow[8], l1v = mrow[9];
        float m1[4] = {m1v.x, m1v.y, m1v.z, m1v.w};
        float l1[4] = {l1v.x, l1v.y, l1v.z, l1v.w};
        float a0[4], a1[4], inv_l[4];
        #pragma unroll
        for (int r = 0; r < 4; ++r) {
            float mn = fmaxf(m_r[r], m1[r]);
            a0[r] = __builtin_amdgcn_exp2f((m_r[r] - mn) * 1.44269504f);
            a1[r] = __builtin_amdgcn_exp2f((m1[r]  - mn) * 1.44269504f);
            inv_l[r] = 1.0f / (l_r[r] * a0[r] + l1[r] * a1[r]);
        }
        float* ob = O + ((size_t)b * SEQ + q0 + w4 * 16) * HD;
        #pragma unroll
        for (int dt = 0; dt < 8; ++dt) {
            float4 o1 = mrow[dt];
            float o1a[4] = {o1.x, o1.y, o1.z, o1.w};
            #pragma unroll
            for (int r = 0; r < 4; ++r) {
                float val = (oacc[dt][r] * a0[r] + o1a[r] * a1[r]) * inv_l[r];
                ob[(size_t)(lg * 4 + r) * HD + lc + dt * 16] = val;
            }
        }
    }
}

extern "C" void kernel_launch(void* const* d_in, const int* in_sizes, int n_in,
                              void* d_out, int out_size, void* d_ws, size_t ws_size,
                              hipStream_t stream) {
    const float* q   = (const float*)d_in[0];
    const float* k   = (const float*)d_in[1];
    const float* v   = (const float*)d_in[2];
    const float* isf = (const float*)d_in[3];
    float* out = (float*)d_out;
    dim3 grid(BATCH * (SEQ / QBLK));   // 512 blocks x 512 threads
    attn_fused<<<grid, 512, 0, stream>>>(q, k, v, isf, out);
}

// Round 11
// 187.738 us; speedup vs baseline: 1.8788x; 1.8788x over previous
//
#include <hip/hip_runtime.h>
#include <hip/hip_bf16.h>

#define BATCH 16
#define SEQ   2048
#define HD    128
#define QBLK  64
#define KVBLK 32
#define KVHALF 1024
#define NTG   (KVHALF / KVBLK)   // 32 KV tiles per group

typedef __attribute__((ext_vector_type(8))) short bf16x8;
typedef __attribute__((ext_vector_type(4))) float f32x4;
typedef __attribute__((ext_vector_type(4))) short s16x4;

__device__ __forceinline__ short f2bf(float x) {
    __hip_bfloat16 h = __float2bfloat16(x);
    return *reinterpret_cast<short*>(&h);
}

// 8 waves = 2 KV-groups x 4 waves. Group g covers kv in [g*1024,(g+1)*1024).
// launch_bounds(512,2): round 9's (512,4) forced VGPR=64 -> scratch spills
// (FETCH 273->855MB). (512,2) allows ~256 VGPR; grid already caps us at
// 2 blocks/CU = 16 waves/CU.
__global__ __launch_bounds__(512, 2)
void attn_fused(const float* __restrict__ Q, const float* __restrict__ K,
                const float* __restrict__ V, const float* __restrict__ ISF,
                float* __restrict__ O)
{
    const int tid  = threadIdx.x;
    const int lane = tid & 63;
    const int wv   = tid >> 6;       // 0..7
    const int w4   = wv & 3;         // wave within group: q-rows [w4*16, w4*16+16)
    const int g    = wv >> 2;        // KV group 0/1
    const int gtid = (w4 << 6) | lane;   // 0..255 within group
    const int lg   = lane >> 4;
    const int lc   = lane & 15;

    const int b    = blockIdx.x >> 5;
    const int q0   = (blockIdx.x & 31) * QBLK;

    // carved shared block: Klds [2 grp][2 buf][4096 shorts] = 32KB,
    // Vtlds [2 grp][5120 shorts] = 20KB; merge buffer (40KB) reuses the front.
    __shared__ __align__(16) char sMem[53248];
    short* Klds  = (short*)sMem;
    short* Vtlds = (short*)(sMem + 32768);

    // ---- Q fragments (A operand): row = q0 + w4*16 + lc, k = ks*32 + lg*8 + j ----
    bf16x8 qf[4];
    {
        const float* qrow = Q + ((size_t)b * SEQ + q0 + w4 * 16 + lc) * HD;
        #pragma unroll
        for (int ks = 0; ks < 4; ++ks) {
            const float* p = qrow + ks * 32 + lg * 8;
            float4 x0 = *reinterpret_cast<const float4*>(p);
            float4 x1 = *reinterpret_cast<const float4*>(p + 4);
            bf16x8 f;
            f[0]=f2bf(x0.x); f[1]=f2bf(x0.y); f[2]=f2bf(x0.z); f[3]=f2bf(x0.w);
            f[4]=f2bf(x1.x); f[5]=f2bf(x1.y); f[6]=f2bf(x1.z); f[7]=f2bf(x1.w);
            qf[ks] = f;
        }
    }

    f32x4 oacc[8];
    #pragma unroll
    for (int i = 0; i < 8; ++i) oacc[i] = (f32x4){0.f, 0.f, 0.f, 0.f};
    float m_r[4] = {-INFINITY, -INFINITY, -INFINITY, -INFINITY};
    float l_r[4] = {0.f, 0.f, 0.f, 0.f};

    const float* kbase = K + (size_t)b * SEQ * HD;
    const float* vbase = V + (size_t)b * SEQ * HD;
    const float* ibase = ISF + ((size_t)b * SEQ + q0 + w4 * 16) * SEQ;
    const int kvbase = g * KVHALF;
    const int kofs   = g * 8192;     // group base into Klds (shorts)
    const int vofs   = g * 5120;     // group base into Vtlds (shorts)

    float4 kreg[4];
    float  vreg[4][4];
    float  isf_cur[8], isf_nxt[8];

    auto LOAD = [&](int kv0) {
        const float* kb = kbase + (size_t)kv0 * HD;
        const float* vb = vbase + (size_t)kv0 * HD;
        #pragma unroll
        for (int r = 0; r < 4; ++r) {
            int idx = r * 256 + gtid;
            kreg[r] = *reinterpret_cast<const float4*>(kb + (size_t)(idx >> 5) * HD + (idx & 31) * 4);
        }
        #pragma unroll
        for (int r = 0; r < 4; ++r) {
            int idx = r * 256 + gtid;
            int d = idx & 127, kq = idx >> 7;
            #pragma unroll
            for (int j = 0; j < 4; ++j)
                vreg[r][j] = vb[(size_t)(kq * 4 + j) * HD + d];
        }
    };
    auto LOAD_ISF = [&](int kv0, float* dst) {
        #pragma unroll
        for (int nt = 0; nt < 2; ++nt)
            #pragma unroll
            for (int r = 0; r < 4; ++r)
                dst[nt * 4 + r] = ibase[(size_t)(lg * 4 + r) * SEQ + kv0 + nt * 16 + lc];
    };
    auto STOREK = [&](int buf) {
        #pragma unroll
        for (int r = 0; r < 4; ++r) {
            int idx = r * 256 + gtid;
            int kvr = idx >> 5, d4 = idx & 31;
            s16x4 s;
            s[0]=f2bf(kreg[r].x); s[1]=f2bf(kreg[r].y); s[2]=f2bf(kreg[r].z); s[3]=f2bf(kreg[r].w);
            int chunk = (d4 >> 1) ^ (kvr & 7);
            *reinterpret_cast<s16x4*>(&Klds[kofs + buf * 4096 + kvr * 128 + chunk * 8 + (d4 & 1) * 4]) = s;
        }
    };
    auto STOREV = [&]() {
        #pragma unroll
        for (int r = 0; r < 4; ++r) {
            int idx = r * 256 + gtid;
            int d = idx & 127, kq = idx >> 7;
            s16x4 s;
            #pragma unroll
            for (int j = 0; j < 4; ++j) s[j] = f2bf(vreg[r][j]);
            *reinterpret_cast<s16x4*>(&Vtlds[vofs + d * 40 + kq * 4]) = s;
        }
    };

    // ---- prologue: stage tile 0 of this group's half ----
    LOAD(kvbase);
    LOAD_ISF(kvbase, isf_cur);
    STOREK(0);
    STOREV();
    __syncthreads();

    int cur = 0;
    for (int t = 0; t < NTG; ++t) {
        const bool more = (t + 1 < NTG);
        if (more) { LOAD(kvbase + (t + 1) * KVBLK); LOAD_ISF(kvbase + (t + 1) * KVBLK, isf_nxt); }

        // ---- S = Q·K^T ----
        f32x4 sacc[2];
        sacc[0] = (f32x4){0.f,0.f,0.f,0.f};
        sacc[1] = (f32x4){0.f,0.f,0.f,0.f};
        #pragma unroll
        for (int nt = 0; nt < 2; ++nt) {
            int n = lc + nt * 16;
            #pragma unroll
            for (int ks = 0; ks < 4; ++ks) {
                int chunk = (ks * 4 + lg) ^ (n & 7);
                bf16x8 bf = *reinterpret_cast<const bf16x8*>(&Klds[kofs + cur * 4096 + n * 128 + chunk * 8]);
                sacc[nt] = __builtin_amdgcn_mfma_f32_16x16x32_bf16(qf[ks], bf, sacc[nt], 0, 0, 0);
            }
        }

        // ---- scale by 1/isf, online softmax ----
        float sc[2][4], pmax[4];
        #pragma unroll
        for (int r = 0; r < 4; ++r) {
            sc[0][r] = sacc[0][r] * __builtin_amdgcn_rcpf(isf_cur[r]);
            sc[1][r] = sacc[1][r] * __builtin_amdgcn_rcpf(isf_cur[4 + r]);
            pmax[r]  = fmaxf(sc[0][r], sc[1][r]);
        }
        #pragma unroll
        for (int msk = 1; msk < 16; msk <<= 1)
            #pragma unroll
            for (int r = 0; r < 4; ++r)
                pmax[r] = fmaxf(pmax[r], __shfl_xor(pmax[r], msk, 64));

        float alpha[4];
        #pragma unroll
        for (int r = 0; r < 4; ++r) {
            float mn = fmaxf(m_r[r], pmax[r]);
            alpha[r] = __builtin_amdgcn_exp2f((m_r[r] - mn) * 1.44269504f);
            m_r[r]   = mn;
        }

        float rsum[4] = {0.f, 0.f, 0.f, 0.f};
        short pb[2][4];
        #pragma unroll
        for (int nt = 0; nt < 2; ++nt)
            #pragma unroll
            for (int r = 0; r < 4; ++r) {
                float p = __builtin_amdgcn_exp2f((sc[nt][r] - m_r[r]) * 1.44269504f);
                rsum[r] += p;
                pb[nt][r] = f2bf(p);
            }
        #pragma unroll
        for (int msk = 1; msk < 16; msk <<= 1)
            #pragma unroll
            for (int r = 0; r < 4; ++r)
                rsum[r] += __shfl_xor(rsum[r], msk, 64);
        #pragma unroll
        for (int r = 0; r < 4; ++r)
            l_r[r] = l_r[r] * alpha[r] + rsum[r];
        #pragma unroll
        for (int dt = 0; dt < 8; ++dt)
            #pragma unroll
            for (int r = 0; r < 4; ++r)
                oacc[dt][r] *= alpha[r];

        // barrier #1: all waves done reading K[cur]; V(t) of every wave visible
        __syncthreads();

        // ---- P: D-layout -> A-frag via this wave's slice of the retired K buffer ----
        short* pw = &Klds[kofs + cur * 4096 + w4 * 1024];   // 640 < 1024 shorts used
        #pragma unroll
        for (int nt = 0; nt < 2; ++nt)
            #pragma unroll
            for (int r = 0; r < 4; ++r)
                pw[(lg * 4 + r) * 40 + nt * 16 + lc] = pb[nt][r];
        bf16x8 pa = *reinterpret_cast<const bf16x8*>(&pw[lc * 40 + lg * 8]);

        // ---- O += P·V ----
        #pragma unroll
        for (int dt = 0; dt < 8; ++dt) {
            bf16x8 vf = *reinterpret_cast<const bf16x8*>(&Vtlds[vofs + (lc + dt * 16) * 40 + lg * 8]);
            oacc[dt] = __builtin_amdgcn_mfma_f32_16x16x32_bf16(pa, vf, oacc[dt], 0, 0, 0);
        }

        if (more) STOREK(cur ^ 1);
        // barrier #2: K(t+1) visible; all PV(t) reads of Vt done -> safe to overwrite V
        __syncthreads();
        if (more) STOREV();

        cur ^= 1;
        #pragma unroll
        for (int i = 0; i < 8; ++i) isf_cur[i] = isf_nxt[i];
    }

    // ---- merge the two KV-half partials (exact online-softmax merge) ----
    __syncthreads();
    float* mbuf = reinterpret_cast<float*>(sMem);   // 256 lanes * 40 floats = 40KB
    float4* mrow = reinterpret_cast<float4*>(mbuf + (size_t)gtid * 40);
    if (g == 1) {
        #pragma unroll
        for (int dt = 0; dt < 8; ++dt)
            mrow[dt] = (float4){oacc[dt][0], oacc[dt][1], oacc[dt][2], oacc[dt][3]};
        mrow[8] = (float4){m_r[0], m_r[1], m_r[2], m_r[3]};
        mrow[9] = (float4){l_r[0], l_r[1], l_r[2], l_r[3]};
    }
    __syncthreads();
    if (g == 0) {
        float4 m1v = mrow[8], l1v = mrow[9];
        float m1[4] = {m1v.x, m1v.y, m1v.z, m1v.w};
        float l1[4] = {l1v.x, l1v.y, l1v.z, l1v.w};
        float a0[4], a1[4], inv_l[4];
        #pragma unroll
        for (int r = 0; r < 4; ++r) {
            float mn = fmaxf(m_r[r], m1[r]);
            a0[r] = __builtin_amdgcn_exp2f((m_r[r] - mn) * 1.44269504f);
            a1[r] = __builtin_amdgcn_exp2f((m1[r]  - mn) * 1.44269504f);
            inv_l[r] = 1.0f / (l_r[r] * a0[r] + l1[r] * a1[r]);
        }
        float* ob = O + ((size_t)b * SEQ + q0 + w4 * 16) * HD;
        #pragma unroll
        for (int dt = 0; dt < 8; ++dt) {
            float4 o1 = mrow[dt];
            float o1a[4] = {o1.x, o1.y, o1.z, o1.w};
            #pragma unroll
            for (int r = 0; r < 4; ++r) {
                float val = (oacc[dt][r] * a0[r] + o1a[r] * a1[r]) * inv_l[r];
                ob[(size_t)(lg * 4 + r) * HD + lc + dt * 16] = val;
            }
        }
    }
}

extern "C" void kernel_launch(void* const* d_in, const int* in_sizes, int n_in,
                              void* d_out, int out_size, void* d_ws, size_t ws_size,
                              hipStream_t stream) {
    const float* q   = (const float*)d_in[0];
    const float* k   = (const float*)d_in[1];
    const float* v   = (const float*)d_in[2];
    const float* isf = (const float*)d_in[3];
    float* out = (float*)d_out;
    dim3 grid(BATCH * (SEQ / QBLK));   // 512 blocks x 512 threads
    attn_fused<<<grid, 512, 0, stream>>>(q, k, v, isf, out);
}

// Round 12
// 165.186 us; speedup vs baseline: 2.1353x; 1.1365x over previous
//
#include <hip/hip_runtime.h>
#include <hip/hip_bf16.h>

#define BATCH 16
#define SEQ   2048
#define HD    128
#define QBLK  64
#define KVBLK 64
#define NT    (SEQ / KVBLK)   // 32 iterations

typedef __attribute__((ext_vector_type(8))) short bf16x8;
typedef __attribute__((ext_vector_type(4))) float f32x4;
typedef __attribute__((ext_vector_type(4))) short s16x4;

__device__ __forceinline__ short f2bf(float x) {
    __hip_bfloat16 h = __float2bfloat16(x);
    return *reinterpret_cast<short*>(&h);
}

// Round-8 structure (best: 148.8us) + KVBLK=64: half the barriers, half the
// softmax shfl rounds per KV row, 2x in-flight bytes per wave.
// Round-11 lesson: bigger blocks don't raise resident waves (occ stuck ~23%)
// -> stay at 256 threads / 4 waves, 2 blocks/CU.
// LDS: Kdbuf 2x16KB + Vt 18KB = 50KB -> 2 blocks/CU fit.
__global__ __launch_bounds__(256, 2)
void attn_fused(const float* __restrict__ Q, const float* __restrict__ K,
                const float* __restrict__ V, const float* __restrict__ ISF,
                float* __restrict__ O)
{
    const int tid  = threadIdx.x;
    const int lane = tid & 63;
    const int wv   = tid >> 6;      // wave 0..3, owns q-rows [wv*16, wv*16+16)
    const int lg   = lane >> 4;     // 16-lane group 0..3
    const int lc   = lane & 15;

    const int b    = blockIdx.x >> 5;
    const int q0   = (blockIdx.x & 31) * QBLK;

    __shared__ short Klds[2][64 * 128];   // bf16, XOR-swizzled 16B chunks, 2x16KB
    __shared__ short Vtlds[128 * 72];     // bf16 transposed V [d][kv], stride 72 shorts
    // P tile reuses the retired K buffer (per-wave 2048-short slice)

    // ---- Q fragments (A operand): row = q0 + wv*16 + lc, k = ks*32 + lg*8 + j ----
    bf16x8 qf[4];
    {
        const float* qrow = Q + ((size_t)b * SEQ + q0 + wv * 16 + lc) * HD;
        #pragma unroll
        for (int ks = 0; ks < 4; ++ks) {
            const float* p = qrow + ks * 32 + lg * 8;
            float4 x0 = *reinterpret_cast<const float4*>(p);
            float4 x1 = *reinterpret_cast<const float4*>(p + 4);
            bf16x8 f;
            f[0]=f2bf(x0.x); f[1]=f2bf(x0.y); f[2]=f2bf(x0.z); f[3]=f2bf(x0.w);
            f[4]=f2bf(x1.x); f[5]=f2bf(x1.y); f[6]=f2bf(x1.z); f[7]=f2bf(x1.w);
            qf[ks] = f;
        }
    }

    f32x4 oacc[8];
    #pragma unroll
    for (int i = 0; i < 8; ++i) oacc[i] = (f32x4){0.f, 0.f, 0.f, 0.f};
    float m_r[4] = {-INFINITY, -INFINITY, -INFINITY, -INFINITY};
    float l_r[4] = {0.f, 0.f, 0.f, 0.f};

    const float* kbase = K + (size_t)b * SEQ * HD;
    const float* vbase = V + (size_t)b * SEQ * HD;
    const float* ibase = ISF + ((size_t)b * SEQ + q0 + wv * 16) * SEQ;

    // prefetch registers for tile t+1 (in flight under tile t's compute)
    float4 kreg[8];
    float  vreg[8][4];
    float  isf_cur[16], isf_nxt[16];

    auto LOAD = [&](int kv0) {
        const float* kb = kbase + (size_t)kv0 * HD;
        const float* vb = vbase + (size_t)kv0 * HD;
        #pragma unroll
        for (int r = 0; r < 8; ++r) {
            int idx = r * 256 + tid;
            kreg[r] = *reinterpret_cast<const float4*>(kb + (size_t)(idx >> 5) * HD + (idx & 31) * 4);
        }
        #pragma unroll
        for (int r = 0; r < 8; ++r) {
            int idx = r * 256 + tid;
            int d = idx & 127, kq = idx >> 7;      // kq 0..15 quad of kv rows
            #pragma unroll
            for (int j = 0; j < 4; ++j)
                vreg[r][j] = vb[(size_t)(kq * 4 + j) * HD + d];
        }
    };
    auto LOAD_ISF = [&](int kv0, float* dst) {
        #pragma unroll
        for (int nt = 0; nt < 4; ++nt)
            #pragma unroll
            for (int r = 0; r < 4; ++r)
                dst[nt * 4 + r] = ibase[(size_t)(lg * 4 + r) * SEQ + kv0 + nt * 16 + lc];
    };
    auto STOREK = [&](int buf) {
        #pragma unroll
        for (int r = 0; r < 8; ++r) {
            int idx = r * 256 + tid;
            int kvr = idx >> 5, d4 = idx & 31;
            s16x4 s;
            s[0]=f2bf(kreg[r].x); s[1]=f2bf(kreg[r].y); s[2]=f2bf(kreg[r].z); s[3]=f2bf(kreg[r].w);
            int chunk = (d4 >> 1) ^ (kvr & 7);
            *reinterpret_cast<s16x4*>(&Klds[buf][kvr * 128 + chunk * 8 + (d4 & 1) * 4]) = s;
        }
    };
    auto STOREV = [&]() {
        #pragma unroll
        for (int r = 0; r < 8; ++r) {
            int idx = r * 256 + tid;
            int d = idx & 127, kq = idx >> 7;
            s16x4 s;
            #pragma unroll
            for (int j = 0; j < 4; ++j) s[j] = f2bf(vreg[r][j]);
            *reinterpret_cast<s16x4*>(&Vtlds[d * 72 + kq * 4]) = s;
        }
    };

    // ---- prologue: tile 0 into buffers ----
    LOAD(0);
    LOAD_ISF(0, isf_cur);
    STOREK(0);
    STOREV();
    __syncthreads();

    int cur = 0;
    for (int t = 0; t < NT; ++t) {
        const bool more = (t + 1 < NT);
        if (more) { LOAD((t + 1) * KVBLK); LOAD_ISF((t + 1) * KVBLK, isf_nxt); }

        // ---- S = Q·K^T (16 rows x 64 cols per wave) ----
        f32x4 sacc[4];
        #pragma unroll
        for (int nt = 0; nt < 4; ++nt) sacc[nt] = (f32x4){0.f,0.f,0.f,0.f};
        #pragma unroll
        for (int nt = 0; nt < 4; ++nt) {
            int n = lc + nt * 16;
            #pragma unroll
            for (int ks = 0; ks < 4; ++ks) {
                int chunk = (ks * 4 + lg) ^ (n & 7);
                bf16x8 bf = *reinterpret_cast<const bf16x8*>(&Klds[cur][n * 128 + chunk * 8]);
                sacc[nt] = __builtin_amdgcn_mfma_f32_16x16x32_bf16(qf[ks], bf, sacc[nt], 0, 0, 0);
            }
        }

        // ---- scale by 1/isf, online softmax over 64 cols ----
        float sc[4][4], pmax[4];
        #pragma unroll
        for (int r = 0; r < 4; ++r) pmax[r] = -INFINITY;
        #pragma unroll
        for (int nt = 0; nt < 4; ++nt)
            #pragma unroll
            for (int r = 0; r < 4; ++r) {
                sc[nt][r] = sacc[nt][r] * __builtin_amdgcn_rcpf(isf_cur[nt * 4 + r]);
                pmax[r] = fmaxf(pmax[r], sc[nt][r]);
            }
        #pragma unroll
        for (int msk = 1; msk < 16; msk <<= 1)
            #pragma unroll
            for (int r = 0; r < 4; ++r)
                pmax[r] = fmaxf(pmax[r], __shfl_xor(pmax[r], msk, 64));

        float alpha[4];
        #pragma unroll
        for (int r = 0; r < 4; ++r) {
            float mn = fmaxf(m_r[r], pmax[r]);
            alpha[r] = __builtin_amdgcn_exp2f((m_r[r] - mn) * 1.44269504f);
            m_r[r]   = mn;
        }

        float rsum[4] = {0.f, 0.f, 0.f, 0.f};
        short pb[4][4];
        #pragma unroll
        for (int nt = 0; nt < 4; ++nt)
            #pragma unroll
            for (int r = 0; r < 4; ++r) {
                float p = __builtin_amdgcn_exp2f((sc[nt][r] - m_r[r]) * 1.44269504f);
                rsum[r] += p;
                pb[nt][r] = f2bf(p);
            }
        #pragma unroll
        for (int msk = 1; msk < 16; msk <<= 1)
            #pragma unroll
            for (int r = 0; r < 4; ++r)
                rsum[r] += __shfl_xor(rsum[r], msk, 64);
        #pragma unroll
        for (int r = 0; r < 4; ++r)
            l_r[r] = l_r[r] * alpha[r] + rsum[r];
        #pragma unroll
        for (int dt = 0; dt < 8; ++dt)
            #pragma unroll
            for (int r = 0; r < 4; ++r)
                oacc[dt][r] *= alpha[r];

        // barrier #1: all waves done QK-reading K[cur]; V(t) stores visible
        __syncthreads();

        // ---- P (16x64): D-layout -> A-frag via this wave's slice of retired K buf ----
        short* pw = &Klds[cur][wv * 2048];   // 16 rows x 72 stride = 1152 < 2048 shorts
        #pragma unroll
        for (int nt = 0; nt < 4; ++nt)
            #pragma unroll
            for (int r = 0; r < 4; ++r)
                pw[(lg * 4 + r) * 72 + nt * 16 + lc] = pb[nt][r];
        bf16x8 pa0 = *reinterpret_cast<const bf16x8*>(&pw[lc * 72 + lg * 8]);
        bf16x8 pa1 = *reinterpret_cast<const bf16x8*>(&pw[lc * 72 + 32 + lg * 8]);

        // land K(t+1) in the other buffer (no one reads it this iter)
        if (more) STOREK(cur ^ 1);

        // ---- O += P·V (two k-halves) ----
        #pragma unroll
        for (int dt = 0; dt < 8; ++dt) {
            const short* vrow = &Vtlds[(lc + dt * 16) * 72];
            bf16x8 vf0 = *reinterpret_cast<const bf16x8*>(&vrow[lg * 8]);
            bf16x8 vf1 = *reinterpret_cast<const bf16x8*>(&vrow[32 + lg * 8]);
            oacc[dt] = __builtin_amdgcn_mfma_f32_16x16x32_bf16(pa0, vf0, oacc[dt], 0, 0, 0);
            oacc[dt] = __builtin_amdgcn_mfma_f32_16x16x32_bf16(pa1, vf1, oacc[dt], 0, 0, 0);
        }

        // barrier #2: PV(t) reads of Vt done everywhere -> safe to overwrite V;
        // K(t+1) visible for next iter
        __syncthreads();
        if (more) STOREV();

        cur ^= 1;
        #pragma unroll
        for (int i = 0; i < 16; ++i) isf_cur[i] = isf_nxt[i];
    }

    // ---- epilogue: divide by l, store fp32 ----
    float* ob = O + ((size_t)b * SEQ + q0 + wv * 16) * HD;
    #pragma unroll
    for (int r = 0; r < 4; ++r) {
        float inv_l = 1.0f / l_r[r];
        float* orow = ob + (size_t)(lg * 4 + r) * HD;
        #pragma unroll
        for (int dt = 0; dt < 8; ++dt)
            orow[lc + dt * 16] = oacc[dt][r] * inv_l;
    }
}

extern "C" void kernel_launch(void* const* d_in, const int* in_sizes, int n_in,
                              void* d_out, int out_size, void* d_ws, size_t ws_size,
                              hipStream_t stream) {
    const float* q   = (const float*)d_in[0];
    const float* k   = (const float*)d_in[1];
    const float* v   = (const float*)d_in[2];
    const float* isf = (const float*)d_in[3];
    float* out = (float*)d_out;
    dim3 grid(BATCH * (SEQ / QBLK));   // 512 blocks x 256 threads
    attn_fused<<<grid, 256, 0, stream>>>(q, k, v, isf, out);
}